// Round 11
// baseline (1501.685 us; speedup 1.0000x reference)
//
#include <hip/hip_runtime.h>
#include <stdint.h>
#include <stddef.h>

// ---------------------------------------------------------------------------
// TextRNN: embed -> BiLSTM(512 steps) -> linear -> softmax   (MI355X gfx950)
//
// R13 (delta vs R12): PUBLISH VIA global_atomic_swap.
// R12 ruled out consumer L1 (buffer_inv each round: no change). Remaining
// suspect: producer store->L2 COMMIT latency. Plain global_store is vmcnt-
// ack'd at WC-buffer acceptance, NOT at L2 visibility; lingering WC lines
// (~1.5-2us) would explain why every store-side variant (drain early/late/
// defer/dual) measured identically, and why R2's ATOMIC protocol saw
// ~0.9us/RT (atomics execute AT the L2 ALU, no WC path).
// Change: the 4 tagged primary words are published with global_atomic_swap
// (no return) -> deterministic early commit at the XCD-L2 bank. Tags stay
// embedded in the data words (word-atomic, mixed-age chunks simply retry).
// Early vmcnt(0) drain dropped (meaningless for L2-committed atomics).
// Everything else byte-identical to R12 (one-variable experiment):
//  - buffer_inv + sc0 poll, one polling wave per producer, s_sleep backoff
//  - sc1 mirror dual-publish (guaranteed progress under any placement)
//  - runtime XCD-discovery grouping (same-XCD groups)
// K0 : transpose/cast Wx,Wh -> bf16 [1024][256]
// K0b: cast emb table f32 -> bf16
// K2 : fused zx + recurrence (32 blocks = 8 groups x 4 cg, 256 thr)
// K3 : logits + softmax (reads primary; dispatch boundary flushes)
// ---------------------------------------------------------------------------

typedef __attribute__((ext_vector_type(8))) short   short8;
typedef __attribute__((ext_vector_type(4))) float   f32x4;
typedef __attribute__((ext_vector_type(4))) unsigned short ushort4v;
typedef __attribute__((ext_vector_type(4))) unsigned int   uint4v;
typedef __attribute__((ext_vector_type(2))) unsigned int   uint2v;

// ws byte offsets
#define EMB16_OFF ((size_t)0)            // 50000*256 bf16 = 25,600,000 B
#define WXT_OFF   ((size_t)25600000)     // 2*1024*256 bf16 = 1,048,576 B
#define WHT_OFF   ((size_t)26648576)     // 2*1024*256 bf16 = 1,048,576 B
#define HBUF_OFF  ((size_t)27697152)     // primary 262144 + mirror 262144 + desc 128
#define WS_NEED   ((size_t)28221568)

__device__ __forceinline__ unsigned short f2bf(float f) {
  unsigned int u = __builtin_bit_cast(unsigned int, f);
  u += 0x7fffu + ((u >> 16) & 1u);            // RNE
  return (unsigned short)(u >> 16);
}
__device__ __forceinline__ float bf2f(unsigned short b) {
  unsigned int u = ((unsigned int)b) << 16;
  return __builtin_bit_cast(float, u);
}
__device__ __forceinline__ float sigf(float x) { return 1.0f / (1.0f + __expf(-x)); }
__device__ __forceinline__ float tanhf_(float x) {
  float t = __expf(-2.0f * fabsf(x));
  float r = (1.0f - t) / (1.0f + t);          // no inf/NaN for any x
  return copysignf(r, x);
}

// ---------------------------------------------------------------------------
// K0: W (f32 [256][1024]) -> Wt (bf16 [1024][256]).  z selects matrix.
__global__ __launch_bounds__(256) void k0_transpose(
    const float* __restrict__ wxf, const float* __restrict__ wxb,
    const float* __restrict__ whf, const float* __restrict__ whb,
    unsigned short* __restrict__ wxt, unsigned short* __restrict__ wht) {
  __shared__ float lds[32][33];
  int mat = blockIdx.z;
  const float* src = (mat == 0) ? wxf : (mat == 1) ? wxb : (mat == 2) ? whf : whb;
  unsigned short* dst = (mat == 0) ? wxt : (mat == 1) ? (wxt + 262144)
                      : (mat == 2) ? wht : (wht + 262144);
  int k0 = blockIdx.x * 32;
  int n0 = blockIdx.y * 32;
  int tx = threadIdx.x & 31, ty = threadIdx.x >> 5;   // ty 0..7
#pragma unroll
  for (int r = 0; r < 4; r++) {
    int k = ty + r * 8;
    lds[k][tx] = src[(size_t)(k0 + k) * 1024 + n0 + tx];
  }
  __syncthreads();
#pragma unroll
  for (int r = 0; r < 4; r++) {
    int n = ty + r * 8;
    dst[(size_t)(n0 + n) * 256 + k0 + tx] = f2bf(lds[tx][n]);
  }
}

// ---------------------------------------------------------------------------
// K0b: emb table f32 -> bf16.  50000*256 = 12.8M elems, 8/thread, 6250 blocks.
__global__ __launch_bounds__(256) void k0b_embcast(
    const float* __restrict__ emb, unsigned short* __restrict__ embbf) {
  size_t i = ((size_t)blockIdx.x * 256 + threadIdx.x) * 8;
  f32x4 v0 = *(const f32x4*)(emb + i);
  f32x4 v1 = *(const f32x4*)(emb + i + 4);
  short8 st;
#pragma unroll
  for (int j = 0; j < 4; j++) {
    st[j]     = (short)f2bf(v0[j]);
    st[4 + j] = (short)f2bf(v1[j]);
  }
  *(short8*)(embbf + i) = st;
}

// ---------------------------------------------------------------------------
// K2: fused zx + recurrence. 32 blocks, 256 thr (4 waves).
// DYNAMIC grouping (R10): rank of key (xcc<<8|bid) in sorted order of all
// 32 keys; group g = rank>>2 -> (d = g>>2, rg = g&3); member cg = rank&3.
// Block (d,rg,cg): batch rows rg*16..+16, h-dims cg*64..+64 (all 4 gates).
// Wave w: dims w*16..+16; lane (q,l16): rows q*4..+4, dim w*16+l16;
// gate-major accumulators (cs = gate) -> c-state in registers.
// hbuf primary: [g][buf][row 16][dim 256] tagged u32 ((t<<16)|bf16),
//               published via global_atomic_swap (L2-commit).
// hbuf mirror : same layout at +65536 words, sc1. desc: +131072 words.
// POLL: wave w<3 polls producer p=(cg+1+w)&3's full tile; lane l:
// row = l>>2, 16-dim quad q4 = l&3; buffer_inv before each round.
__global__ __launch_bounds__(256, 1) void k2_rnn(
    const int* __restrict__ tokens, const unsigned short* __restrict__ embbf,
    const unsigned short* __restrict__ wxt,   // [2][1024][256] bf16
    const unsigned short* __restrict__ wht,   // [2][1024][256] bf16
    const float* __restrict__ bf_, const float* __restrict__ bb_,
    unsigned int* __restrict__ hbufw) {
  int bx = blockIdx.x;
  int tid = threadIdx.x;
  int w = tid >> 6, lane = tid & 63, q = lane >> 4, l16 = lane & 15;

  // ---- XCD discovery & dynamic group assignment ----
  unsigned int* desc = hbufw + 131072;
  {
    unsigned int xcc = __builtin_amdgcn_s_getreg((31 << 11) | 20) & 0xffu;  // HW_REG_XCC_ID
    if (tid == 0) {
      unsigned int v = 0x100u | xcc;
      asm volatile("global_store_dword %0, %1, off sc1"
                   :: "v"(desc + bx), "v"(v) : "memory");
    }
  }
  int g, cg;
  {
    const unsigned int* dp = desc + (lane & 31);
    unsigned int dv;
    while (true) {
      asm volatile("buffer_inv\n\tglobal_load_dword %0, %1, off sc1\n\ts_waitcnt vmcnt(0)"
                   : "=&v"(dv) : "v"(dp) : "memory");
      if (__all((dv & 0x100u) != 0u)) break;
    }
    unsigned int key = ((dv & 0xffu) << 8) | (unsigned int)(lane & 31);
    int rank = 0;
#pragma unroll
    for (int j = 0; j < 32; ++j) {
      unsigned int kj = __shfl(key, j);
      rank += (kj < key) ? 1 : 0;
    }
    int myrank = __shfl(rank, bx);   // our block's rank (bx < 32)
    g  = myrank >> 2;
    cg = myrank & 3;
  }
  int d  = g >> 2;
  int rg = g & 3;

  __shared__ unsigned short wx2[32][256][8];    // Wx slice, interleaved: 131072 B
  __shared__ unsigned short hl[2][32][16][8];   // h tiles, interleaved:   16384 B

  // ---- preload Wx slice (block cols: gate*256 + cg*64 + dl) into wx2 ----
  const unsigned short* wxd = wxt + (size_t)d * 262144;
  for (int it = 0; it < 32; ++it) {
    int idx = it * 256 + tid;                 // 8192 16B-chunks
    int cl = idx & 255, ch = idx >> 8;        // cl = cs*64+dl, ch = kt*4+q
    int gcol = (cl >> 6) * 256 + cg * 64 + (cl & 63);
    *(short8*)(&wx2[ch][cl][0]) = *(const short8*)(wxd + (size_t)gcol * 256 + ch * 8);
  }

  // ---- Wh B-fragments resident in registers (128 regs/lane) ----
  const unsigned short* whd = wht + (size_t)d * 262144;
  short8 bfr[4][8];
#pragma unroll
  for (int cs = 0; cs < 4; cs++) {
    const unsigned short* wp = whd + (size_t)(cs * 256 + cg * 64 + w * 16 + l16) * 256;
#pragma unroll
    for (int kt = 0; kt < 8; kt++)
      bfr[cs][kt] = *(const short8*)(wp + kt * 32 + q * 8);
  }

  // zero h LDS tiles (h0 = 0)
  {
    unsigned int* hlw = (unsigned int*)&hl[0][0][0][0];
    for (int i = tid; i < 4096; i += 256) hlw[i] = 0;
  }
  __syncthreads();

  const float* bias = d ? bb_ : bf_;
  float bv[4];
#pragma unroll
  for (int cs = 0; cs < 4; cs++) bv[cs] = bias[cs * 256 + cg * 64 + w * 16 + l16];

  float cst[4] = {0.f, 0.f, 0.f, 0.f};        // c for (row=q*4+r, dim=w*16+l16)
  unsigned int* hb = hbufw + (size_t)g * 8192;              // primary
  int srow  = (q * 4) * 256 + cg * 64 + w * 16 + l16;       // producer base
  const int* tokrow = tokens + (rg * 16 + l16) * 512;

  // poll geometry (waves 0..2 only)
  int p_w   = (cg + 1 + w) & 3;               // this wave's producer
  int prow2 = lane >> 2;                      // row 0..15
  int pq4   = lane & 3;                       // 16-dim quad within 64
  int pbase2 = prow2 * 256 + p_w * 64 + pq4 * 16;   // word offset

  int limit = 16;                              // adaptive sc0 poll budget

  // prologue: emb row for t=0
  short8 ea[8];
  {
    int ts0 = d ? 511 : 0;
    int tok0 = tokrow[ts0];
    const unsigned short* er = embbf + (size_t)tok0 * 256 + q * 8;
#pragma unroll
    for (int kt = 0; kt < 8; ++kt) ea[kt] = *(const short8*)(er + kt * 32);
  }

  for (int t = 0; t < 512; ++t) {
    int buf = t & 1;
    int tsn = (t < 511) ? (d ? 510 - t : t + 1) : 0;   // next-step token col
    int tok_n = tokrow[tsn];

    // ---- zx tile MFMA (uses prefetched ea; h-independent; overlaps the
    //      L2-commit of our previous-step atomics / in-flight mirrors) ----
    f32x4 acc[4];
#pragma unroll
    for (int cs = 0; cs < 4; ++cs) acc[cs] = {0.f, 0.f, 0.f, 0.f};
#pragma unroll
    for (int kt = 0; kt < 8; ++kt) {
#pragma unroll
      for (int cs = 0; cs < 4; ++cs) {
        short8 xb = *(const short8*)(&wx2[kt * 4 + q][cs * 64 + w * 16 + l16][0]);
        acc[cs] = __builtin_amdgcn_mfma_f32_16x16x32_bf16(ea[kt], xb, acc[cs], 0, 0, 0);
      }
    }

    // ---- poll (waves 0..2): producer p_w's full 16x64 tile.
    // buffer_inv + sc0 loads read true XCD-L2; the atomics committed there.
    unsigned int tg = (unsigned int)t << 16;
    if (w < 3) {
      const unsigned int* qp = hb + buf * 4096 + pbase2;
      uint4v s0, s1, s2, s3;
      bool got = false;
      for (int it = 0; it < limit; ++it) {
        asm volatile(
            "buffer_inv\n\t"
            "global_load_dwordx4 %[s0], %[pp], off sc0\n\t"
            "global_load_dwordx4 %[s1], %[pp], off offset:16 sc0\n\t"
            "global_load_dwordx4 %[s2], %[pp], off offset:32 sc0\n\t"
            "global_load_dwordx4 %[s3], %[pp], off offset:48 sc0\n\t"
            "s_waitcnt vmcnt(0)"
            : [s0] "=&v"(s0), [s1] "=&v"(s1), [s2] "=&v"(s2), [s3] "=&v"(s3)
            : [pp] "v"(qp)
            : "memory");
        unsigned int bad = (s0[0] ^ tg) | (s0[1] ^ tg) | (s0[2] ^ tg) | (s0[3] ^ tg)
                         | (s1[0] ^ tg) | (s1[1] ^ tg) | (s1[2] ^ tg) | (s1[3] ^ tg)
                         | (s2[0] ^ tg) | (s2[1] ^ tg) | (s2[2] ^ tg) | (s2[3] ^ tg)
                         | (s3[0] ^ tg) | (s3[1] ^ tg) | (s3[2] ^ tg) | (s3[3] ^ tg);
        if (__all((bad & 0xffff0000u) == 0)) { got = true; break; }
        __builtin_amdgcn_s_sleep(2);           // backoff
      }
      if (!got) {
        limit >>= 1;                           // sticky decay toward sc1-only
        const unsigned int* mp = qp + 65536;
        while (true) {
          asm volatile(
              "buffer_inv\n\t"
              "global_load_dwordx4 %[s0], %[pp], off sc1\n\t"
              "global_load_dwordx4 %[s1], %[pp], off offset:16 sc1\n\t"
              "global_load_dwordx4 %[s2], %[pp], off offset:32 sc1\n\t"
              "global_load_dwordx4 %[s3], %[pp], off offset:48 sc1\n\t"
              "s_waitcnt vmcnt(0)"
              : [s0] "=&v"(s0), [s1] "=&v"(s1), [s2] "=&v"(s2), [s3] "=&v"(s3)
              : [pp] "v"(mp)
              : "memory");
          unsigned int bad = (s0[0] ^ tg) | (s0[1] ^ tg) | (s0[2] ^ tg) | (s0[3] ^ tg)
                           | (s1[0] ^ tg) | (s1[1] ^ tg) | (s1[2] ^ tg) | (s1[3] ^ tg)
                           | (s2[0] ^ tg) | (s2[1] ^ tg) | (s2[2] ^ tg) | (s2[3] ^ tg)
                           | (s3[0] ^ tg) | (s3[1] ^ tg) | (s3[2] ^ tg) | (s3[3] ^ tg);
          if (__all((bad & 0xffff0000u) == 0)) break;
          __builtin_amdgcn_s_sleep(4);
        }
      }
      // deposit 16 bf16 into hl[buf] chunks (p_w*8 + pq4*2, +1), row prow2
      {
        uint4v d0, d1;
        d0[0] = __builtin_amdgcn_perm(s0[1], s0[0], 0x05040100u);
        d0[1] = __builtin_amdgcn_perm(s0[3], s0[2], 0x05040100u);
        d0[2] = __builtin_amdgcn_perm(s1[1], s1[0], 0x05040100u);
        d0[3] = __builtin_amdgcn_perm(s1[3], s1[2], 0x05040100u);
        d1[0] = __builtin_amdgcn_perm(s2[1], s2[0], 0x05040100u);
        d1[1] = __builtin_amdgcn_perm(s2[3], s2[2], 0x05040100u);
        d1[2] = __builtin_amdgcn_perm(s3[1], s3[0], 0x05040100u);
        d1[3] = __builtin_amdgcn_perm(s3[3], s3[2], 0x05040100u);
        int ch0 = p_w * 8 + pq4 * 2;
        *(uint4v*)(&hl[buf][ch0][prow2][0])     = d0;
        *(uint4v*)(&hl[buf][ch0 + 1][prow2][0]) = d1;
      }
    }

    // ---- emb prefetch for t+1 (flies during h-GEMM + epilogue) ----
    short8 ean[8];
    {
      const unsigned short* ern = embbf + (size_t)tok_n * 256 + q * 8;
#pragma unroll
      for (int kt = 0; kt < 8; ++kt) ean[kt] = *(const short8*)(ern + kt * 32);
    }

    __syncthreads();   // hl[buf] complete; also publishes prev epilogue writes

    // ---- h GEMM: A from LDS tile (conflict-free b128), B from regs ----
#pragma unroll
    for (int kt = 0; kt < 8; ++kt) {
      short8 ha = *(const short8*)(&hl[buf][kt * 4 + q][l16][0]);
#pragma unroll
      for (int cs = 0; cs < 4; ++cs)
        acc[cs] = __builtin_amdgcn_mfma_f32_16x16x32_bf16(ha, bfr[cs][kt], acc[cs], 0, 0, 0);
    }

    // ---- epilogue: gates, c/h update, LDS own-dims, atomic publish ----
    unsigned int* hwn = hb + ((buf ^ 1) * 4096) + srow;
    unsigned int wtag = ((unsigned int)(t + 1)) << 16;
    int dim = cg * 64 + w * 16 + l16;
    int chO = dim >> 3, eO = dim & 7;
    unsigned int sw[4];
#pragma unroll
    for (int r = 0; r < 4; ++r) {
      float iv = sigf(acc[0][r] + bv[0]);
      float fv = sigf(acc[1][r] + bv[1]);
      float gv = tanhf_(acc[2][r] + bv[2]);
      float ov = sigf(acc[3][r] + bv[3]);
      cst[r] = fv * cst[r] + iv * gv;
      float hv = ov * tanhf_(cst[r]);
      unsigned short h16 = f2bf(hv);
      sw[r] = wtag | (unsigned int)h16;
      hl[buf ^ 1][chO][q * 4 + r][eO] = h16;
    }
    // primary publish via global_atomic_swap (no return): commits AT the
    // XCD-L2 ALU — no WC-buffer lingering. Then 4 sc1 mirrors (guaranteed
    // path), undrained; next poll's vmcnt(0) covers all.
    {
      unsigned int* hwm = hwn + 65536;
      asm volatile(
          "global_atomic_swap %[p], %[v0], off\n\t"
          "global_atomic_swap %[p], %[v1], off offset:1024\n\t"
          "global_atomic_swap %[p], %[v2], off offset:2048\n\t"
          "global_atomic_swap %[p], %[v3], off offset:3072\n\t"
          "global_store_dword %[m], %[v0], off sc1\n\t"
          "global_store_dword %[m], %[v1], off offset:1024 sc1\n\t"
          "global_store_dword %[m], %[v2], off offset:2048 sc1\n\t"
          "global_store_dword %[m], %[v3], off offset:3072 sc1"
          :: [p] "v"(hwn), [m] "v"(hwm), [v0] "v"(sw[0]), [v1] "v"(sw[1]),
             [v2] "v"(sw[2]), [v3] "v"(sw[3])
          : "memory");
    }

    // rotate emb prefetch
#pragma unroll
    for (int kt = 0; kt < 8; ++kt) ea[kt] = ean[kt];
  }
}

// ---------------------------------------------------------------------------
// K3: logits + softmax. 64 blocks (one per batch) x 64 threads (one wave).
// Final h_512 (tag 512, buf0) read from the PRIMARY buffers (atomic-written);
// the k2->k3 dispatch boundary flushes caches (standard visibility).
__global__ __launch_bounds__(64) void k3_out(
    const unsigned int* __restrict__ hbufw,
    const float* __restrict__ wout, const float* __restrict__ bout,
    float* __restrict__ out) {
  int b = blockIdx.x, tid = threadIdx.x;
  int rg = b >> 4, r = b & 15;
  const unsigned int* hf  = hbufw + (size_t)rg * 8192 + r * 256;           // dir0 buf0
  const unsigned int* hbk = hbufw + 32768 + (size_t)rg * 8192 + r * 256;   // dir1 buf0
  float p[10];
#pragma unroll
  for (int l = 0; l < 10; l++) p[l] = 0.f;
  for (int k = tid; k < 512; k += 64) {
    unsigned int wd = (k < 256) ? hf[k] : hbk[k - 256];
    float f = bf2f((unsigned short)(wd & 0xffffu));
    const float* wr = wout + k * 10;
#pragma unroll
    for (int l = 0; l < 10; l++) p[l] += f * wr[l];
  }
#pragma unroll
  for (int off = 32; off; off >>= 1)
#pragma unroll
    for (int l = 0; l < 10; l++) p[l] += __shfl_down(p[l], off);
  if (tid == 0) {
    float lg[10], m = -1e30f;
#pragma unroll
    for (int l = 0; l < 10; l++) { lg[l] = p[l] + bout[l]; m = fmaxf(m, lg[l]); }
    float sum = 0.f;
#pragma unroll
    for (int l = 0; l < 10; l++) { lg[l] = __expf(lg[l] - m); sum += lg[l]; }
    float inv = 1.0f / sum;
#pragma unroll
    for (int l = 0; l < 10; l++) out[b * 10 + l] = lg[l] * inv;
  }
}

// ---------------------------------------------------------------------------
extern "C" void kernel_launch(void* const* d_in, const int* in_sizes, int n_in,
                              void* d_out, int out_size, void* d_ws, size_t ws_size,
                              hipStream_t stream) {
  const int*   tokens = (const int*)d_in[0];
  const float* emb    = (const float*)d_in[1];
  const float* wxf    = (const float*)d_in[2];
  const float* whf    = (const float*)d_in[3];
  const float* bf_    = (const float*)d_in[4];
  const float* wxb    = (const float*)d_in[5];
  const float* whb    = (const float*)d_in[6];
  const float* bb_    = (const float*)d_in[7];
  const float* wout   = (const float*)d_in[8];
  const float* bout   = (const float*)d_in[9];
  float* out = (float*)d_out;

  char* ws = (char*)d_ws;
  unsigned short* embbf = (unsigned short*)(ws + EMB16_OFF);
  unsigned short* wxt   = (unsigned short*)(ws + WXT_OFF);
  unsigned short* wht   = (unsigned short*)(ws + WHT_OFF);
  unsigned int*   hbufw = (unsigned int*)(ws + HBUF_OFF);
  (void)ws_size; (void)in_sizes; (void)n_in; (void)out_size;   // needs WS_NEED bytes

  // zero h0 (tag 0 == step 0) in primary, mirror, and desc area
  hipMemsetAsync(ws + HBUF_OFF, 0, 524416, stream);

  k0_transpose<<<dim3(8, 32, 4), 256, 0, stream>>>(wxf, wxb, whf, whb, wxt, wht);
  k0b_embcast<<<6250, 256, 0, stream>>>(emb, embbf);
  k2_rnn<<<32, 256, 0, stream>>>(tokens, embbf, wxt, wht, bf_, bb_, hbufw);
  k3_out<<<64, 64, 0, stream>>>(hbufw, wout, bout, out);
}

// Round 12
// 1288.838 us; speedup vs baseline: 1.1651x; 1.1651x over previous
//
#include <hip/hip_runtime.h>
#include <stdint.h>
#include <stddef.h>

// ---------------------------------------------------------------------------
// TextRNN: embed -> BiLSTM(512 steps) -> linear -> softmax   (MI355X gfx950)
//
// R14 (delta vs R12 — R13's MALL-atomics reverted):
// * SELF-LOAD WC FLUSH: after the 4 sc0 primary stores, issue 4 sc0 LOADS
//   of the same addresses (load-hit-store forces the WC line to flush to
//   the XCD-L2 promptly). Loads are issued, never waited (next poll's
//   vmcnt(0) drains them) -> off critical path. This is the one untested
//   producer-commit mechanism: R13's atomics bypassed WC but paid the
//   MALL RT (device-scope) — WRITE_SIZE doubled, perf regressed.
// * PUBLISH-FIRST epilogue: compute all 4 sw words, publish immediately,
//   THEN do own-dim LDS writes + sc1 mirrors (~0.1us earlier T_pub).
// * s_sleep removed from the sc0 poll (detection delay); kept in the sc1
//   fallback (MALL protection).
// Retained from R12: buffer_inv + sc0 poll, one polling wave per producer,
// sc1 mirror dual-publish (hang-proof any placement), runtime XCD-discovery
// grouping, fused zx, tokens-in-LDS, Wx-in-LDS, Wh-in-regs.
// K0 : transpose/cast Wx,Wh -> bf16 [1024][256]
// K0b: cast emb table f32 -> bf16
// K2 : fused zx + recurrence (32 blocks = 8 groups x 4 cg, 256 thr)
// K3 : logits + softmax (reads primary; dispatch boundary flushes)
// ---------------------------------------------------------------------------

typedef __attribute__((ext_vector_type(8))) short   short8;
typedef __attribute__((ext_vector_type(4))) float   f32x4;
typedef __attribute__((ext_vector_type(4))) unsigned short ushort4v;
typedef __attribute__((ext_vector_type(4))) unsigned int   uint4v;
typedef __attribute__((ext_vector_type(2))) unsigned int   uint2v;

// ws byte offsets
#define EMB16_OFF ((size_t)0)            // 50000*256 bf16 = 25,600,000 B
#define WXT_OFF   ((size_t)25600000)     // 2*1024*256 bf16 = 1,048,576 B
#define WHT_OFF   ((size_t)26648576)     // 2*1024*256 bf16 = 1,048,576 B
#define HBUF_OFF  ((size_t)27697152)     // primary 262144 + mirror 262144 + desc 128
#define WS_NEED   ((size_t)28221568)

__device__ __forceinline__ unsigned short f2bf(float f) {
  unsigned int u = __builtin_bit_cast(unsigned int, f);
  u += 0x7fffu + ((u >> 16) & 1u);            // RNE
  return (unsigned short)(u >> 16);
}
__device__ __forceinline__ float bf2f(unsigned short b) {
  unsigned int u = ((unsigned int)b) << 16;
  return __builtin_bit_cast(float, u);
}
__device__ __forceinline__ float sigf(float x) { return 1.0f / (1.0f + __expf(-x)); }
__device__ __forceinline__ float tanhf_(float x) {
  float t = __expf(-2.0f * fabsf(x));
  float r = (1.0f - t) / (1.0f + t);          // no inf/NaN for any x
  return copysignf(r, x);
}

// ---------------------------------------------------------------------------
// K0: W (f32 [256][1024]) -> Wt (bf16 [1024][256]).  z selects matrix.
__global__ __launch_bounds__(256) void k0_transpose(
    const float* __restrict__ wxf, const float* __restrict__ wxb,
    const float* __restrict__ whf, const float* __restrict__ whb,
    unsigned short* __restrict__ wxt, unsigned short* __restrict__ wht) {
  __shared__ float lds[32][33];
  int mat = blockIdx.z;
  const float* src = (mat == 0) ? wxf : (mat == 1) ? wxb : (mat == 2) ? whf : whb;
  unsigned short* dst = (mat == 0) ? wxt : (mat == 1) ? (wxt + 262144)
                      : (mat == 2) ? wht : (wht + 262144);
  int k0 = blockIdx.x * 32;
  int n0 = blockIdx.y * 32;
  int tx = threadIdx.x & 31, ty = threadIdx.x >> 5;   // ty 0..7
#pragma unroll
  for (int r = 0; r < 4; r++) {
    int k = ty + r * 8;
    lds[k][tx] = src[(size_t)(k0 + k) * 1024 + n0 + tx];
  }
  __syncthreads();
#pragma unroll
  for (int r = 0; r < 4; r++) {
    int n = ty + r * 8;
    dst[(size_t)(n0 + n) * 256 + k0 + tx] = f2bf(lds[tx][n]);
  }
}

// ---------------------------------------------------------------------------
// K0b: emb table f32 -> bf16.  50000*256 = 12.8M elems, 8/thread, 6250 blocks.
__global__ __launch_bounds__(256) void k0b_embcast(
    const float* __restrict__ emb, unsigned short* __restrict__ embbf) {
  size_t i = ((size_t)blockIdx.x * 256 + threadIdx.x) * 8;
  f32x4 v0 = *(const f32x4*)(emb + i);
  f32x4 v1 = *(const f32x4*)(emb + i + 4);
  short8 st;
#pragma unroll
  for (int j = 0; j < 4; j++) {
    st[j]     = (short)f2bf(v0[j]);
    st[4 + j] = (short)f2bf(v1[j]);
  }
  *(short8*)(embbf + i) = st;
}

// ---------------------------------------------------------------------------
// K2: fused zx + recurrence. 32 blocks, 256 thr (4 waves).
// DYNAMIC grouping (R10): rank of key (xcc<<8|bid) in sorted order of all
// 32 keys; group g = rank>>2 -> (d = g>>2, rg = g&3); member cg = rank&3.
// Block (d,rg,cg): batch rows rg*16..+16, h-dims cg*64..+64 (all 4 gates).
// Wave w: dims w*16..+16; lane (q,l16): rows q*4..+4, dim w*16+l16;
// gate-major accumulators (cs = gate) -> c-state in registers.
// hbuf primary: [g][buf][row 16][dim 256] tagged u32 ((t<<16)|bf16), sc0
//               + self-load WC flush.
// hbuf mirror : same layout at +65536 words, sc1. desc: +131072 words.
// POLL: wave w<3 polls producer p=(cg+1+w)&3's full tile; lane l:
// row = l>>2, 16-dim quad q4 = l&3; buffer_inv before each round.
__global__ __launch_bounds__(256, 1) void k2_rnn(
    const int* __restrict__ tokens, const unsigned short* __restrict__ embbf,
    const unsigned short* __restrict__ wxt,   // [2][1024][256] bf16
    const unsigned short* __restrict__ wht,   // [2][1024][256] bf16
    const float* __restrict__ bf_, const float* __restrict__ bb_,
    unsigned int* __restrict__ hbufw) {
  int bx = blockIdx.x;
  int tid = threadIdx.x;
  int w = tid >> 6, lane = tid & 63, q = lane >> 4, l16 = lane & 15;

  // ---- XCD discovery & dynamic group assignment ----
  unsigned int* desc = hbufw + 131072;
  {
    unsigned int xcc = __builtin_amdgcn_s_getreg((31 << 11) | 20) & 0xffu;  // HW_REG_XCC_ID
    if (tid == 0) {
      unsigned int v = 0x100u | xcc;
      asm volatile("global_store_dword %0, %1, off sc1"
                   :: "v"(desc + bx), "v"(v) : "memory");
    }
  }
  int g, cg;
  {
    const unsigned int* dp = desc + (lane & 31);
    unsigned int dv;
    while (true) {
      asm volatile("buffer_inv\n\tglobal_load_dword %0, %1, off sc1\n\ts_waitcnt vmcnt(0)"
                   : "=&v"(dv) : "v"(dp) : "memory");
      if (__all((dv & 0x100u) != 0u)) break;
    }
    unsigned int key = ((dv & 0xffu) << 8) | (unsigned int)(lane & 31);
    int rank = 0;
#pragma unroll
    for (int j = 0; j < 32; ++j) {
      unsigned int kj = __shfl(key, j);
      rank += (kj < key) ? 1 : 0;
    }
    int myrank = __shfl(rank, bx);   // our block's rank (bx < 32)
    g  = myrank >> 2;
    cg = myrank & 3;
  }
  int d  = g >> 2;
  int rg = g & 3;

  __shared__ unsigned short wx2[32][256][8];    // Wx slice, interleaved: 131072 B
  __shared__ unsigned short hl[2][32][16][8];   // h tiles, interleaved:   16384 B

  // ---- preload Wx slice (block cols: gate*256 + cg*64 + dl) into wx2 ----
  const unsigned short* wxd = wxt + (size_t)d * 262144;
  for (int it = 0; it < 32; ++it) {
    int idx = it * 256 + tid;                 // 8192 16B-chunks
    int cl = idx & 255, ch = idx >> 8;        // cl = cs*64+dl, ch = kt*4+q
    int gcol = (cl >> 6) * 256 + cg * 64 + (cl & 63);
    *(short8*)(&wx2[ch][cl][0]) = *(const short8*)(wxd + (size_t)gcol * 256 + ch * 8);
  }

  // ---- Wh B-fragments resident in registers (128 regs/lane) ----
  const unsigned short* whd = wht + (size_t)d * 262144;
  short8 bfr[4][8];
#pragma unroll
  for (int cs = 0; cs < 4; cs++) {
    const unsigned short* wp = whd + (size_t)(cs * 256 + cg * 64 + w * 16 + l16) * 256;
#pragma unroll
    for (int kt = 0; kt < 8; kt++)
      bfr[cs][kt] = *(const short8*)(wp + kt * 32 + q * 8);
  }

  // zero h LDS tiles (h0 = 0)
  {
    unsigned int* hlw = (unsigned int*)&hl[0][0][0][0];
    for (int i = tid; i < 4096; i += 256) hlw[i] = 0;
  }
  __syncthreads();

  const float* bias = d ? bb_ : bf_;
  float bv[4];
#pragma unroll
  for (int cs = 0; cs < 4; cs++) bv[cs] = bias[cs * 256 + cg * 64 + w * 16 + l16];

  float cst[4] = {0.f, 0.f, 0.f, 0.f};        // c for (row=q*4+r, dim=w*16+l16)
  unsigned int* hb = hbufw + (size_t)g * 8192;              // primary
  int srow  = (q * 4) * 256 + cg * 64 + w * 16 + l16;       // producer base
  const int* tokrow = tokens + (rg * 16 + l16) * 512;

  // poll geometry (waves 0..2 only)
  int p_w   = (cg + 1 + w) & 3;               // this wave's producer
  int prow2 = lane >> 2;                      // row 0..15
  int pq4   = lane & 3;                       // 16-dim quad within 64
  int pbase2 = prow2 * 256 + p_w * 64 + pq4 * 16;   // word offset

  int limit = 16;                              // adaptive sc0 poll budget

  // prologue: emb row for t=0
  short8 ea[8];
  {
    int ts0 = d ? 511 : 0;
    int tok0 = tokrow[ts0];
    const unsigned short* er = embbf + (size_t)tok0 * 256 + q * 8;
#pragma unroll
    for (int kt = 0; kt < 8; ++kt) ea[kt] = *(const short8*)(er + kt * 32);
  }

  for (int t = 0; t < 512; ++t) {
    int buf = t & 1;
    int tsn = (t < 511) ? (d ? 510 - t : t + 1) : 0;   // next-step token col
    int tok_n = tokrow[tsn];

    // ---- zx tile MFMA (uses prefetched ea; h-independent; overlaps the
    //      flush/commit of our previous-step publishes) ----
    f32x4 acc[4];
#pragma unroll
    for (int cs = 0; cs < 4; ++cs) acc[cs] = {0.f, 0.f, 0.f, 0.f};
#pragma unroll
    for (int kt = 0; kt < 8; ++kt) {
#pragma unroll
      for (int cs = 0; cs < 4; ++cs) {
        short8 xb = *(const short8*)(&wx2[kt * 4 + q][cs * 64 + w * 16 + l16][0]);
        acc[cs] = __builtin_amdgcn_mfma_f32_16x16x32_bf16(ea[kt], xb, acc[cs], 0, 0, 0);
      }
    }

    // ---- poll (waves 0..2): producer p_w's full 16x64 tile.
    // buffer_inv + sc0 loads; no sleep (detection latency matters more
    // than port pressure — R11 showed backoff buys nothing).
    unsigned int tg = (unsigned int)t << 16;
    if (w < 3) {
      const unsigned int* qp = hb + buf * 4096 + pbase2;
      uint4v s0, s1, s2, s3;
      bool got = false;
      for (int it = 0; it < limit; ++it) {
        asm volatile(
            "buffer_inv\n\t"
            "global_load_dwordx4 %[s0], %[pp], off sc0\n\t"
            "global_load_dwordx4 %[s1], %[pp], off offset:16 sc0\n\t"
            "global_load_dwordx4 %[s2], %[pp], off offset:32 sc0\n\t"
            "global_load_dwordx4 %[s3], %[pp], off offset:48 sc0\n\t"
            "s_waitcnt vmcnt(0)"
            : [s0] "=&v"(s0), [s1] "=&v"(s1), [s2] "=&v"(s2), [s3] "=&v"(s3)
            : [pp] "v"(qp)
            : "memory");
        unsigned int bad = (s0[0] ^ tg) | (s0[1] ^ tg) | (s0[2] ^ tg) | (s0[3] ^ tg)
                         | (s1[0] ^ tg) | (s1[1] ^ tg) | (s1[2] ^ tg) | (s1[3] ^ tg)
                         | (s2[0] ^ tg) | (s2[1] ^ tg) | (s2[2] ^ tg) | (s2[3] ^ tg)
                         | (s3[0] ^ tg) | (s3[1] ^ tg) | (s3[2] ^ tg) | (s3[3] ^ tg);
        if (__all((bad & 0xffff0000u) == 0)) { got = true; break; }
      }
      if (!got) {
        limit >>= 1;                           // sticky decay toward sc1-only
        const unsigned int* mp = qp + 65536;
        while (true) {
          asm volatile(
              "buffer_inv\n\t"
              "global_load_dwordx4 %[s0], %[pp], off sc1\n\t"
              "global_load_dwordx4 %[s1], %[pp], off offset:16 sc1\n\t"
              "global_load_dwordx4 %[s2], %[pp], off offset:32 sc1\n\t"
              "global_load_dwordx4 %[s3], %[pp], off offset:48 sc1\n\t"
              "s_waitcnt vmcnt(0)"
              : [s0] "=&v"(s0), [s1] "=&v"(s1), [s2] "=&v"(s2), [s3] "=&v"(s3)
              : [pp] "v"(mp)
              : "memory");
          unsigned int bad = (s0[0] ^ tg) | (s0[1] ^ tg) | (s0[2] ^ tg) | (s0[3] ^ tg)
                           | (s1[0] ^ tg) | (s1[1] ^ tg) | (s1[2] ^ tg) | (s1[3] ^ tg)
                           | (s2[0] ^ tg) | (s2[1] ^ tg) | (s2[2] ^ tg) | (s2[3] ^ tg)
                           | (s3[0] ^ tg) | (s3[1] ^ tg) | (s3[2] ^ tg) | (s3[3] ^ tg);
          if (__all((bad & 0xffff0000u) == 0)) break;
          __builtin_amdgcn_s_sleep(4);
        }
      }
      // deposit 16 bf16 into hl[buf] chunks (p_w*8 + pq4*2, +1), row prow2
      {
        uint4v d0, d1;
        d0[0] = __builtin_amdgcn_perm(s0[1], s0[0], 0x05040100u);
        d0[1] = __builtin_amdgcn_perm(s0[3], s0[2], 0x05040100u);
        d0[2] = __builtin_amdgcn_perm(s1[1], s1[0], 0x05040100u);
        d0[3] = __builtin_amdgcn_perm(s1[3], s1[2], 0x05040100u);
        d1[0] = __builtin_amdgcn_perm(s2[1], s2[0], 0x05040100u);
        d1[1] = __builtin_amdgcn_perm(s2[3], s2[2], 0x05040100u);
        d1[2] = __builtin_amdgcn_perm(s3[1], s3[0], 0x05040100u);
        d1[3] = __builtin_amdgcn_perm(s3[3], s3[2], 0x05040100u);
        int ch0 = p_w * 8 + pq4 * 2;
        *(uint4v*)(&hl[buf][ch0][prow2][0])     = d0;
        *(uint4v*)(&hl[buf][ch0 + 1][prow2][0]) = d1;
      }
    }

    // ---- emb prefetch for t+1 (flies during h-GEMM + epilogue) ----
    short8 ean[8];
    {
      const unsigned short* ern = embbf + (size_t)tok_n * 256 + q * 8;
#pragma unroll
      for (int kt = 0; kt < 8; ++kt) ean[kt] = *(const short8*)(ern + kt * 32);
    }

    __syncthreads();   // hl[buf] complete; also publishes prev epilogue writes

    // ---- h GEMM: A from LDS tile (conflict-free b128), B from regs ----
#pragma unroll
    for (int kt = 0; kt < 8; ++kt) {
      short8 ha = *(const short8*)(&hl[buf][kt * 4 + q][l16][0]);
#pragma unroll
      for (int cs = 0; cs < 4; ++cs)
        acc[cs] = __builtin_amdgcn_mfma_f32_16x16x32_bf16(ha, bfr[cs][kt], acc[cs], 0, 0, 0);
    }

    // ---- epilogue (publish-first): gates + c/h update for all 4 rows,
    //      publish IMMEDIATELY (4 sc0 stores + 4 self-load WC flushes),
    //      then LDS own-dim writes, then 4 sc1 mirrors. ----
    unsigned int* hwn = hb + ((buf ^ 1) * 4096) + srow;
    unsigned int wtag = ((unsigned int)(t + 1)) << 16;
    int dim = cg * 64 + w * 16 + l16;
    int chO = dim >> 3, eO = dim & 7;
    unsigned int sw[4];
    unsigned short h16v[4];
#pragma unroll
    for (int r = 0; r < 4; ++r) {
      float iv = sigf(acc[0][r] + bv[0]);
      float fv = sigf(acc[1][r] + bv[1]);
      float gv = tanhf_(acc[2][r] + bv[2]);
      float ov = sigf(acc[3][r] + bv[3]);
      cst[r] = fv * cst[r] + iv * gv;
      float hv = ov * tanhf_(cst[r]);
      h16v[r] = f2bf(hv);
      sw[r] = wtag | (unsigned int)h16v[r];
    }
    // publish: 4 sc0 primaries, then 4 sc0 self-loads of the SAME addresses
    // (load-hit-store forces each WC line to flush into the XCD-L2 NOW).
    // Self-load results are dummies; everything drains in the next poll's
    // vmcnt(0), off the critical path.
    {
      unsigned int dmy0, dmy1, dmy2, dmy3;
      asm volatile(
          "global_store_dword %[p], %[v0], off sc0\n\t"
          "global_store_dword %[p], %[v1], off offset:1024 sc0\n\t"
          "global_store_dword %[p], %[v2], off offset:2048 sc0\n\t"
          "global_store_dword %[p], %[v3], off offset:3072 sc0\n\t"
          "global_load_dword %[d0], %[p], off sc0\n\t"
          "global_load_dword %[d1], %[p], off offset:1024 sc0\n\t"
          "global_load_dword %[d2], %[p], off offset:2048 sc0\n\t"
          "global_load_dword %[d3], %[p], off offset:3072 sc0"
          : [d0] "=&v"(dmy0), [d1] "=&v"(dmy1), [d2] "=&v"(dmy2), [d3] "=&v"(dmy3)
          : [p] "v"(hwn), [v0] "v"(sw[0]), [v1] "v"(sw[1]),
            [v2] "v"(sw[2]), [v3] "v"(sw[3])
          : "memory");
    }
    // own-dim LDS writes (consumed after next step's barrier)
#pragma unroll
    for (int r = 0; r < 4; ++r)
      hl[buf ^ 1][chO][q * 4 + r][eO] = h16v[r];
    // sc1 mirrors (guaranteed path), undrained
    {
      unsigned int* hwm = hwn + 65536;
      asm volatile(
          "global_store_dword %[m], %[v0], off sc1\n\t"
          "global_store_dword %[m], %[v1], off offset:1024 sc1\n\t"
          "global_store_dword %[m], %[v2], off offset:2048 sc1\n\t"
          "global_store_dword %[m], %[v3], off offset:3072 sc1"
          :: [m] "v"(hwm), [v0] "v"(sw[0]), [v1] "v"(sw[1]),
             [v2] "v"(sw[2]), [v3] "v"(sw[3])
          : "memory");
    }

    // rotate emb prefetch
#pragma unroll
    for (int kt = 0; kt < 8; ++kt) ea[kt] = ean[kt];
  }
}

// ---------------------------------------------------------------------------
// K3: logits + softmax. 64 blocks (one per batch) x 64 threads (one wave).
// Final h_512 (tag 512, buf0) read from the PRIMARY buffers; the k2->k3
// dispatch boundary flushes caches (standard cross-kernel visibility).
__global__ __launch_bounds__(64) void k3_out(
    const unsigned int* __restrict__ hbufw,
    const float* __restrict__ wout, const float* __restrict__ bout,
    float* __restrict__ out) {
  int b = blockIdx.x, tid = threadIdx.x;
  int rg = b >> 4, r = b & 15;
  const unsigned int* hf  = hbufw + (size_t)rg * 8192 + r * 256;           // dir0 buf0
  const unsigned int* hbk = hbufw + 32768 + (size_t)rg * 8192 + r * 256;   // dir1 buf0
  float p[10];
#pragma unroll
  for (int l = 0; l < 10; l++) p[l] = 0.f;
  for (int k = tid; k < 512; k += 64) {
    unsigned int wd = (k < 256) ? hf[k] : hbk[k - 256];
    float f = bf2f((unsigned short)(wd & 0xffffu));
    const float* wr = wout + k * 10;
#pragma unroll
    for (int l = 0; l < 10; l++) p[l] += f * wr[l];
  }
#pragma unroll
  for (int off = 32; off; off >>= 1)
#pragma unroll
    for (int l = 0; l < 10; l++) p[l] += __shfl_down(p[l], off);
  if (tid == 0) {
    float lg[10], m = -1e30f;
#pragma unroll
    for (int l = 0; l < 10; l++) { lg[l] = p[l] + bout[l]; m = fmaxf(m, lg[l]); }
    float sum = 0.f;
#pragma unroll
    for (int l = 0; l < 10; l++) { lg[l] = __expf(lg[l] - m); sum += lg[l]; }
    float inv = 1.0f / sum;
#pragma unroll
    for (int l = 0; l < 10; l++) out[b * 10 + l] = lg[l] * inv;
  }
}

// ---------------------------------------------------------------------------
extern "C" void kernel_launch(void* const* d_in, const int* in_sizes, int n_in,
                              void* d_out, int out_size, void* d_ws, size_t ws_size,
                              hipStream_t stream) {
  const int*   tokens = (const int*)d_in[0];
  const float* emb    = (const float*)d_in[1];
  const float* wxf    = (const float*)d_in[2];
  const float* whf    = (const float*)d_in[3];
  const float* bf_    = (const float*)d_in[4];
  const float* wxb    = (const float*)d_in[5];
  const float* whb    = (const float*)d_in[6];
  const float* bb_    = (const float*)d_in[7];
  const float* wout   = (const float*)d_in[8];
  const float* bout   = (const float*)d_in[9];
  float* out = (float*)d_out;

  char* ws = (char*)d_ws;
  unsigned short* embbf = (unsigned short*)(ws + EMB16_OFF);
  unsigned short* wxt   = (unsigned short*)(ws + WXT_OFF);
  unsigned short* wht   = (unsigned short*)(ws + WHT_OFF);
  unsigned int*   hbufw = (unsigned int*)(ws + HBUF_OFF);
  (void)ws_size; (void)in_sizes; (void)n_in; (void)out_size;   // needs WS_NEED bytes

  // zero h0 (tag 0 == step 0) in primary, mirror, and desc area
  hipMemsetAsync(ws + HBUF_OFF, 0, 524416, stream);

  k0_transpose<<<dim3(8, 32, 4), 256, 0, stream>>>(wxf, wxb, whf, whb, wxt, wht);
  k0b_embcast<<<6250, 256, 0, stream>>>(emb, embbf);
  k2_rnn<<<32, 256, 0, stream>>>(tokens, embbf, wxt, wht, bf_, bb_, hbufw);
  k3_out<<<64, 64, 0, stream>>>(hbufw, wout, bout, out);
}